// Round 2
// baseline (280.217 us; speedup 1.0000x reference)
//
#include <hip/hip_runtime.h>
#include <hip/hip_fp16.h>
#include <math.h>
#include <stdint.h>

#define HH 512
#define WW 512
#define NIMG 24
#define CCH 3
#define TAU 0.25f
#define TVEPS 2e-4f
#define NUMEL 262144.0f

// Fused-tile geometry: 64x64 owned, halo 2 -> 68x68 staged.
#define LSF 69   // row stride (words) for PT/OA in LDS (odd -> conflict-free strips)
#define LSH 70   // row stride (halves) for IM in LDS (even -> 4B-aligned pair stores)

// ws layout (256 MiB):
//   byte 0     : sc — 2 slots x 128 floats; slot s at sc+128*s:
//                [0..23]=E_prev, [32..55]=E_init, int[64..87]=done, int[96..119]=last_k
//                slot (m&1) holds state S_{2m-2} after fused kernel m runs.
//   byte 4096  : sums — float [2][4][NIMG][64]; slot = m&1; arrays 0=da,1=na,2=db,3=nb
//                (step0 writes its accn into slot0/arr1)
//   byte 65536 : imgh (__half, 24*512*512)
//   byte 12648448 : ptA (uint32 packed half2, 24*512*512)
//   byte 37814272 : ptB

__device__ __forceinline__ float2 h2f(uint32_t v) {
    __half2 h; *reinterpret_cast<uint32_t*>(&h) = v;
    return __half22float2(h);
}
__device__ __forceinline__ uint32_t f2h2(float a, float b) {
    __half2 h = __floats2half2_rn(a, b);
    return *reinterpret_cast<uint32_t*>(&h);
}
__device__ __forceinline__ void h4_to_f(uint2 hv, float* f) {
    float2 a = h2f(hv.x), b = h2f(hv.y);
    f[0] = a.x; f[1] = a.y; f[2] = b.x; f[3] = b.y;
}

struct Smem {
    uint32_t PT[68 * LSF];   // pt_in -> (in-place) pt_a
    float    OA[68 * LSF];   // out_a -> (after sync) out_b
    __half   IM[68 * LSH];   // imgh tile
};

__device__ __forceinline__ int SUMIX(int slot, int arr, int im) {
    return ((slot * 4 + arr) * NIMG + im) * 64;
}

// ---- staging: pt (uint2 pairs) + imgh (uint32 pairs), OOB -> 0 ----
__device__ void stage_pt_im(Smem& S, const uint32_t* __restrict__ ptg,
                            const __half* __restrict__ hI,
                            int x0, int y0, int tid) {
    for (int idx = tid; idx < 68 * 34; idx += 256) {
        int r = idx / 34, mq = idx - r * 34;
        int c = 2 * mq;
        int y = y0 - 2 + r, x = x0 - 2 + c;
        uint2 pv = make_uint2(0u, 0u);
        uint32_t iv = 0u;
        if ((unsigned)y < (unsigned)HH && (unsigned)x < (unsigned)WW) {
            size_t off = (size_t)y * WW + x;
            pv = *(const uint2*)(ptg + off);
            iv = *(const uint32_t*)(hI + off);
        }
        S.PT[r * LSF + c] = pv.x;
        S.PT[r * LSF + c + 1] = pv.y;
        *(uint32_t*)&S.IM[r * LSH + c] = iv;
    }
}

// ---- phase 1: out_a = im + div(pt_in), region r,c in [1,68); OOB px auto-0 ----
template <bool ACC>
__device__ float phase_outA(Smem& S, int tid) {
    float acc = 0.f;
    for (int idx = tid; idx < 67 * 67; idx += 256) {
        int r = idx / 67, c = idx - r * 67;
        r += 1; c += 1;
        float2 cf = h2f(S.PT[r * LSF + c]);
        float up = h2f(S.PT[(r - 1) * LSF + c]).x;
        float lf = h2f(S.PT[r * LSF + c - 1]).y;
        float im = __half2float(S.IM[r * LSH + c]);
        float oa = im + (-(cf.x + cf.y) + up + lf);
        S.OA[r * LSF + c] = oa;
        if (ACC) {
            if (r >= 2 && r < 66 && c >= 2 && c < 66) {
                float d = oa - im;
                acc += d * d;
            }
        }
    }
    return acc;
}

// ---- phase 2: pt_a = (pt_in - tau*g_a) / (1 + (tau/w)|g_a|), region [1,67) ----
template <bool ACC>
__device__ float phase_ptA(Smem& S, int x0, int y0, int tid, float tw) {
    float acc = 0.f;
    for (int idx = tid; idx < 66 * 66; idx += 256) {
        int r = idx / 66, c = idx - r * 66;
        r += 1; c += 1;
        int y = y0 - 2 + r, x = x0 - 2 + c;
        if ((unsigned)y < (unsigned)HH && (unsigned)x < (unsigned)WW) {
            float o = S.OA[r * LSF + c];
            float g0 = (y < HH - 1) ? S.OA[(r + 1) * LSF + c] - o : 0.f;
            float g1 = (x < WW - 1) ? S.OA[r * LSF + c + 1] - o : 0.f;
            float ss2 = g0 * g0 + g1 * g1;
            float nrm = (ss2 > 0.f) ? sqrtf(ss2) : 0.f;
            if (ACC) {
                if (r >= 2 && r < 66 && c >= 2 && c < 66) acc += nrm;
            }
            float inv = __builtin_amdgcn_rcpf(1.f + tw * nrm);
            float2 cf = h2f(S.PT[r * LSF + c]);
            S.PT[r * LSF + c] = f2h2((cf.x - TAU * g0) * inv, (cf.y - TAU * g1) * inv);
        } else {
            S.PT[r * LSF + c] = 0u;
        }
    }
    return acc;
}

// ---- phase 3: out_b = im + div(pt_a), region [2,67); OOB px auto-0 ----
template <bool ACC>
__device__ float phase_outB(Smem& S, int tid) {
    float acc = 0.f;
    for (int idx = tid; idx < 65 * 65; idx += 256) {
        int r = idx / 65, c = idx - r * 65;
        r += 2; c += 2;
        float2 cf = h2f(S.PT[r * LSF + c]);
        float im = __half2float(S.IM[r * LSH + c]);
        float ob = im + (-(cf.x + cf.y) + h2f(S.PT[(r - 1) * LSF + c]).x
                         + h2f(S.PT[r * LSF + c - 1]).y);
        S.OA[r * LSF + c] = ob;
        if (ACC) {
            if (r < 66 && c < 66) {
                float d = ob - im;
                acc += d * d;
            }
        }
    }
    return acc;
}

// ---- phase 4: pt_b on owned 64x64, coalesced uint4 store; returns accn_b ----
__device__ float phase_ptB_store(Smem& S, uint32_t* __restrict__ poutI,
                                 int x0, int y0, int tid, float tw) {
    const int tx = tid & 15, ry = tid >> 4;
    const int gxb = x0 + 4 * tx;
    float acc = 0.f;
    #pragma unroll
    for (int i = 0; i < 4; ++i) {
        int gy = y0 + ry + 16 * i;
        int r = 2 + ry + 16 * i;
        uint32_t pv[4];
        #pragma unroll
        for (int j = 0; j < 4; ++j) {
            int c = 2 + 4 * tx + j;
            float o = S.OA[r * LSF + c];
            float g0 = (gy < HH - 1) ? S.OA[(r + 1) * LSF + c] - o : 0.f;
            float g1 = (gxb + j < WW - 1) ? S.OA[r * LSF + c + 1] - o : 0.f;
            float ss2 = g0 * g0 + g1 * g1;
            float nrm = (ss2 > 0.f) ? sqrtf(ss2) : 0.f;
            acc += nrm;
            float inv = __builtin_amdgcn_rcpf(1.f + tw * nrm);
            float2 cf = h2f(S.PT[r * LSF + c]);
            pv[j] = f2h2((cf.x - TAU * g0) * inv, (cf.y - TAU * g1) * inv);
        }
        *(uint4*)(poutI + (size_t)gy * WW + gxb) = make_uint4(pv[0], pv[1], pv[2], pv[3]);
    }
    return acc;
}

__device__ __forceinline__ void red4_store(float a, float b, float c, float d,
                                           float* pa, float* pb, float* pc, float* pdd,
                                           int tid) {
    for (int off = 32; off > 0; off >>= 1) {
        a += __shfl_down(a, off, 64);
        b += __shfl_down(b, off, 64);
        c += __shfl_down(c, off, 64);
        d += __shfl_down(d, off, 64);
    }
    __shared__ float sr[4][4];
    int wave = tid >> 6, lane = tid & 63;
    if (lane == 0) { sr[0][wave] = a; sr[1][wave] = b; sr[2][wave] = c; sr[3][wave] = d; }
    __syncthreads();
    if (tid == 0) {
        *pa = (sr[0][0] + sr[0][1]) + (sr[0][2] + sr[0][3]);
        *pb = (sr[1][0] + sr[1][1]) + (sr[1][2] + sr[1][3]);
        *pc = (sr[2][0] + sr[2][1]) + (sr[2][2] + sr[2][3]);
        *pdd = (sr[3][0] + sr[3][1]) + (sr[3][2] + sr[3][3]);
    }
}

// =========================== iteration 0 ===========================
__global__ __launch_bounds__(256, 4) void tv_step0(
    const float* __restrict__ img, const float* __restrict__ weight,
    __half* __restrict__ imgh, uint32_t* __restrict__ ptout,
    float* __restrict__ pn0)
{
    const int im = blockIdx.z;
    const int bid = blockIdx.y * 8 + blockIdx.x;
    const float w = weight[im / CCH];
    const int x0 = blockIdx.x * 64, y0 = blockIdx.y * 64;
    const float* imgI = img + (size_t)im * HH * WW;
    __half* hI = imgh + (size_t)im * HH * WW;
    uint32_t* pI = ptout + (size_t)im * HH * WW;
    __shared__ float s[65][68];
    const int tid = threadIdx.x;
    const int tx = tid & 15, ry = tid >> 4;
    const int gx = x0 + 4 * tx;

    float o[4][4];
    #pragma unroll
    for (int i = 0; i < 4; ++i) {
        int ey = ry + 16 * i, gy = y0 + ey;
        float4 v = *(const float4*)(imgI + (size_t)gy * WW + gx);
        o[i][0] = v.x; o[i][1] = v.y; o[i][2] = v.z; o[i][3] = v.w;
        *(float4*)&s[ey][4 * tx] = v;
    }
    if (tx == 15 && x0 + 64 < WW) {
        #pragma unroll
        for (int i = 0; i < 4; ++i) {
            int ey = ry + 16 * i, gy = y0 + ey;
            s[ey][64] = imgI[(size_t)gy * WW + x0 + 64];
        }
    }
    if (ry == 0 && y0 + 64 < HH) {
        *(float4*)&s[64][4 * tx] = *(const float4*)(imgI + (size_t)(y0 + 64) * WW + gx);
    }
    __syncthreads();

    float accn = 0.f;
    const float tw = TAU / w;
    #pragma unroll
    for (int i = 0; i < 4; ++i) {
        int ey = ry + 16 * i, gy = y0 + ey;
        float4 dn = *(float4*)&s[ey + 1][4 * tx];
        float rt_sh = __shfl_down(o[i][0], 1, 64);
        float rt = (tx == 15) ? s[ey][64] : rt_sh;
        float dnv[4] = {dn.x, dn.y, dn.z, dn.w};
        uint32_t pv[4];
        #pragma unroll
        for (int j = 0; j < 4; ++j) {
            float ov = o[i][j];
            float g0 = (gy < HH - 1) ? dnv[j] - ov : 0.f;
            float rn = (j < 3) ? o[i][j + 1] : rt;
            float g1 = (gx + j < WW - 1) ? rn - ov : 0.f;
            float ss2 = g0 * g0 + g1 * g1;
            float nrm = (ss2 > 0.f) ? sqrtf(ss2) : 0.f;
            accn += nrm;
            float inv = __builtin_amdgcn_rcpf(1.f + tw * nrm);
            pv[j] = f2h2(-TAU * g0 * inv, -TAU * g1 * inv);
        }
        size_t off = (size_t)gy * WW + gx;
        *(uint4*)(pI + off) = make_uint4(pv[0], pv[1], pv[2], pv[3]);
        *(uint2*)(hI + off) = make_uint2(f2h2(o[i][0], o[i][1]), f2h2(o[i][2], o[i][3]));
    }
    // wave reduce -> pn0
    for (int off = 32; off > 0; off >>= 1) accn += __shfl_down(accn, off, 64);
    __shared__ float sr[4];
    if ((tid & 63) == 0) sr[tid >> 6] = accn;
    __syncthreads();
    if (tid == 0) pn0[im * 64 + bid] = (sr[0] + sr[1]) + (sr[2] + sr[3]);
}

// ================== fused pair: iterations (2m-1, 2m) ==================
__global__ __launch_bounds__(256, 3) void tv_fused(
    int m,
    const __half* __restrict__ imgh, const float* __restrict__ weight,
    const uint32_t* __restrict__ pt_in, uint32_t* __restrict__ pt_out,
    float* __restrict__ sc, float* __restrict__ sums)
{
    const int im = blockIdx.z;
    const int bid = blockIdx.y * 8 + blockIdx.x;
    const int tid = threadIdx.x;
    const float w = weight[im / CCH];

    // --- replay head: derive S_{2m-2} from previous kernel's partials ---
    __shared__ int sh_done;
    {
        const int sIn = (m - 1) & 1;
        if (tid < 64) {
            float da = 0.f, na = 0.f, db = 0.f, nb = 0.f;
            if (m == 1) {
                na = sums[SUMIX(0, 1, im) + tid];   // step0's accn
            } else {
                da = sums[SUMIX(sIn, 0, im) + tid];
                na = sums[SUMIX(sIn, 1, im) + tid];
                db = sums[SUMIX(sIn, 2, im) + tid];
                nb = sums[SUMIX(sIn, 3, im) + tid];
            }
            for (int off = 32; off > 0; off >>= 1) {
                da += __shfl_down(da, off, 64);
                na += __shfl_down(na, off, 64);
                db += __shfl_down(db, off, 64);
                nb += __shfl_down(nb, off, 64);
            }
            if (tid == 0) {
                float Eprev, Einit; int done, lastk;
                if (m == 1) {
                    float E0 = w * na / NUMEL;
                    Eprev = E0; Einit = E0; done = 0; lastk = 0;
                } else {
                    const float* sI = sc + sIn * 128;
                    Eprev = sI[im]; Einit = sI[32 + im];
                    done = ((const int*)sI)[64 + im];
                    lastk = ((const int*)sI)[96 + im];
                    if (!done) {
                        float Et = (da + w * na) / NUMEL;           // iter 2m-3
                        if (fabsf(Eprev - Et) < TVEPS * Einit) { done = 1; lastk = 2 * m - 3; }
                        else {
                            Eprev = Et;
                            Et = (db + w * nb) / NUMEL;             // iter 2m-2
                            if (fabsf(Eprev - Et) < TVEPS * Einit) { done = 1; lastk = 2 * m - 2; }
                            else Eprev = Et;
                        }
                    }
                }
                if (bid == 0) {
                    float* sO = sc + (m & 1) * 128;
                    sO[im] = Eprev; sO[32 + im] = Einit;
                    ((int*)sO)[64 + im] = done;
                    ((int*)sO)[96 + im] = lastk;
                }
                sh_done = done;
            }
        }
    }
    __syncthreads();
    if (sh_done) return;  // frozen image: preserve buffers

    const int x0 = blockIdx.x * 64, y0 = blockIdx.y * 64;
    const float tw = TAU / w;
    const uint32_t* pinI = pt_in + (size_t)im * HH * WW;
    uint32_t* poutI = pt_out + (size_t)im * HH * WW;
    const __half* hI = imgh + (size_t)im * HH * WW;

    __shared__ Smem S;
    stage_pt_im(S, pinI, hI, x0, y0, tid);
    __syncthreads();
    float a_d = phase_outA<true>(S, tid);
    __syncthreads();
    float a_n = phase_ptA<true>(S, x0, y0, tid, tw);
    __syncthreads();
    float b_d = phase_outB<true>(S, tid);
    __syncthreads();
    float b_n = phase_ptB_store(S, poutI, x0, y0, tid, tw);

    const int sOut = m & 1;
    red4_store(a_d, a_n, b_d, b_n,
               &sums[SUMIX(sOut, 0, im) + bid], &sums[SUMIX(sOut, 1, im) + bid],
               &sums[SUMIX(sOut, 2, im) + bid], &sums[SUMIX(sOut, 3, im) + bid], tid);
}

// =========================== epilogue ===========================
// k = last executed iteration. out = img(fp32) + div(pt_{k-1}).
// k odd or 9 -> pt_{k-1} materialized; k even -> recompute pt_{k-1} from pt_{k-2}.
__global__ __launch_bounds__(256, 3) void tv_out(
    const float* __restrict__ img, float* __restrict__ out,
    const uint32_t* __restrict__ ptA, const uint32_t* __restrict__ ptB,
    const __half* __restrict__ imgh, const float* __restrict__ weight,
    const float* __restrict__ sc, const float* __restrict__ sums)
{
    const int im = blockIdx.z;
    const int tid = threadIdx.x;
    const float w = weight[im / CCH];

    __shared__ int2 shk;
    {
        const float* sI = sc;  // slot 0 = S_6 (written by fused m=4's head... m=4 writes slot 0)
        int done = ((const int*)sI)[64 + im];
        int lastk = ((const int*)sI)[96 + im];
        if (!done && tid < 64) {
            float da = sums[SUMIX(0, 0, im) + tid];
            float na = sums[SUMIX(0, 1, im) + tid];
            float db = sums[SUMIX(0, 2, im) + tid];
            float nb = sums[SUMIX(0, 3, im) + tid];
            for (int off = 32; off > 0; off >>= 1) {
                da += __shfl_down(da, off, 64);
                na += __shfl_down(na, off, 64);
                db += __shfl_down(db, off, 64);
                nb += __shfl_down(nb, off, 64);
            }
            if (tid == 0) {
                float Eprev = sI[im], Einit = sI[32 + im];
                float Et = (da + w * na) / NUMEL;                  // iter 7
                if (fabsf(Eprev - Et) < TVEPS * Einit) { done = 1; lastk = 7; }
                else {
                    Eprev = Et;
                    Et = (db + w * nb) / NUMEL;                    // iter 8
                    if (fabsf(Eprev - Et) < TVEPS * Einit) { done = 1; lastk = 8; }
                }
            }
        }
        if (tid == 0) { shk.x = done; shk.y = lastk; }
    }
    __syncthreads();
    const int k = shk.x ? shk.y : 9;

    const float* imgI = img + (size_t)im * HH * WW;
    float* outI = out + (size_t)im * HH * WW;
    const int x0 = blockIdx.x * 64, y0 = blockIdx.y * 64;
    const int tx = tid & 15, ry = tid >> 4;
    const int gx = x0 + 4 * tx;

    if (k & 1) {
        // k in {1,3,5,7,9}: pt_{k-1} even, materialized.
        // pt_0->A, pt_2->B, pt_4->A, pt_6->B, pt_8->A.
        const uint32_t* p = ((((k - 1) >> 1) & 1) ? ptB : ptA) + (size_t)im * HH * WW;
        #pragma unroll
        for (int i = 0; i < 4; ++i) {
            int gy = y0 + ry + 16 * i;
            size_t off = (size_t)gy * WW + gx;
            uint4 cv = *(const uint4*)(p + off);
            uint4 uv = make_uint4(0u, 0u, 0u, 0u);
            if (gy > 0) uv = *(const uint4*)(p + off - WW);
            uint32_t lf = (gx > 0) ? p[off - 1] : 0u;
            float4 iv = *(const float4*)(imgI + off);
            uint32_t cc[4] = {cv.x, cv.y, cv.z, cv.w};
            uint32_t uu[4] = {uv.x, uv.y, uv.z, uv.w};
            uint32_t lt[4] = {lf, cv.x, cv.y, cv.z};
            float ivv[4] = {iv.x, iv.y, iv.z, iv.w};
            float r[4];
            #pragma unroll
            for (int j = 0; j < 4; ++j) {
                float2 cf = h2f(cc[j]);
                r[j] = ivv[j] + (-(cf.x + cf.y) + h2f(uu[j]).x + h2f(lt[j]).y);
            }
            *(float4*)(outI + off) = make_float4(r[0], r[1], r[2], r[3]);
        }
    } else {
        // k in {2,4,6,8}: recompute pt_{k-1} from preserved pt_{k-2}.
        // pt_0->A, pt_2->B, pt_4->A, pt_6->B.
        const uint32_t* p = ((((k - 2) >> 1) & 1) ? ptB : ptA) + (size_t)im * HH * WW;
        const __half* hI = imgh + (size_t)im * HH * WW;
        const float tw = TAU / w;
        __shared__ Smem S;
        stage_pt_im(S, p, hI, x0, y0, tid);
        __syncthreads();
        phase_outA<false>(S, tid);        // out_{k-1}
        __syncthreads();
        phase_ptA<false>(S, x0, y0, tid, tw);   // pt_{k-1} in S.PT
        __syncthreads();
        #pragma unroll
        for (int i = 0; i < 4; ++i) {
            int gy = y0 + ry + 16 * i;
            int r = 2 + ry + 16 * i;
            size_t off = (size_t)gy * WW + gx;
            float4 iv = *(const float4*)(imgI + off);
            float ivv[4] = {iv.x, iv.y, iv.z, iv.w};
            float rr[4];
            #pragma unroll
            for (int j = 0; j < 4; ++j) {
                int c = 2 + 4 * tx + j;
                float2 cf = h2f(S.PT[r * LSF + c]);
                float up = h2f(S.PT[(r - 1) * LSF + c]).x;
                float lf = h2f(S.PT[r * LSF + c - 1]).y;
                rr[j] = ivv[j] + (-(cf.x + cf.y) + up + lf);
            }
            *(float4*)(outI + off) = make_float4(rr[0], rr[1], rr[2], rr[3]);
        }
    }
}

extern "C" void kernel_launch(void* const* d_in, const int* in_sizes, int n_in,
                              void* d_out, int out_size, void* d_ws, size_t ws_size,
                              hipStream_t stream)
{
    const float* img = (const float*)d_in[0];
    const float* weight = (const float*)d_in[1];
    float* out = (float*)d_out;
    float* sc = (float*)d_ws;
    float* sums = (float*)((char*)d_ws + 4096);
    __half* imgh = (__half*)((char*)d_ws + 65536);
    uint32_t* ptA = (uint32_t*)((char*)d_ws + 12648448);
    uint32_t* ptB = (uint32_t*)((char*)d_ws + 37814272);

    dim3 grid(8, 8, NIMG);
    dim3 block(256);

    // iteration 0 -> pt_0 in A; accn into sums slot0/arr1
    tv_step0<<<grid, block, 0, stream>>>(img, weight, imgh, ptA,
                                         sums + (0 * 4 + 1) * NIMG * 64);

    // fused pairs: m=1..4 cover iterations 1..8
    // m odd: A->B, m even: B->A  =>  pt_2:B, pt_4:A, pt_6:B, pt_8:A
    for (int m = 1; m <= 4; ++m) {
        uint32_t* pin  = (m & 1) ? ptA : ptB;
        uint32_t* pout = (m & 1) ? ptB : ptA;
        tv_fused<<<grid, block, 0, stream>>>(m, imgh, weight, pin, pout, sc, sums);
    }

    // iteration 9's pt is dead; epilogue replays iters 7,8 convergence and
    // emits out = img + div(pt_{k-1}).
    tv_out<<<grid, block, 0, stream>>>(img, out, ptA, ptB, imgh, weight, sc, sums);
}